// Round 1
// baseline (665.800 us; speedup 1.0000x reference)
//
#include <hip/hip_runtime.h>

#define WAVE 64
#define BLOCK 256
#define GRID 2048
#define EPSF 1e-8f

typedef float f4 __attribute__((ext_vector_type(4)));

__device__ __forceinline__ float sq4(f4 v, float acc) {
    return fmaf(v.x, v.x, fmaf(v.y, v.y, fmaf(v.z, v.z, fmaf(v.w, v.w, acc))));
}

__global__ __launch_bounds__(BLOCK) void cosine_loss_kernel(
    const float* __restrict__ logits,
    const int* __restrict__ labels,
    float* __restrict__ out,
    int N, int C, float inv_n)
{
    const int lane    = threadIdx.x & (WAVE - 1);
    const int wave_id = (blockIdx.x * BLOCK + threadIdx.x) >> 6;
    const int n_waves = (gridDim.x * BLOCK) >> 6;

    const int nvec = C >> 2;          // full float4 chunks per row
    const int tail = nvec << 2;       // first scalar-tail column

    float local = 0.0f;

    // Super-groups of up to 64 rows per wave; lane k owns row g0 + k*n_waves.
    // All label+dot gathers happen ONCE per super-group (one dependent-load
    // chain per wave instead of one per 4-row group), so the streaming loop
    // below has no vmcnt(0) drains from dependent gathers.
    for (int g0 = wave_id; g0 < N; g0 += (n_waves << 6)) {
        const long long my_r = (long long)g0 + (long long)lane * (long long)n_waves;
        float my_dot = 0.0f;
        if (my_r < (long long)N) {
            const int lbl = labels[my_r];
            my_dot = logits[(size_t)my_r * (size_t)C + (size_t)lbl];
        }

        int nrows = (N - g0 + n_waves - 1) / n_waves;   // valid rows this super-group
        if (nrows > 64) nrows = 64;

        int k = 0;

        if (nvec <= 256) {
            // ---- fast path (C <= 1024): whole row = <=4 chunks/lane.
            // Issue all 16 f4 loads (16 KB/wave) before any FMA -> deep MLP.
            const int c0 = lane;
            const int c1 = lane + 64;
            const int c2 = lane + 128;
            const int c3 = lane + 192;
            const bool k0 = c0 < nvec;
            const bool k1 = c1 < nvec;
            const bool k2 = c2 < nvec;
            const bool k3 = c3 < nvec;
            const f4 fz = {0.0f, 0.0f, 0.0f, 0.0f};

            for (; k + 3 < nrows; k += 4) {
                const size_t r0 = (size_t)g0 + (size_t)(k    ) * n_waves;
                const size_t r1 = (size_t)g0 + (size_t)(k + 1) * n_waves;
                const size_t r2 = (size_t)g0 + (size_t)(k + 2) * n_waves;
                const size_t r3 = (size_t)g0 + (size_t)(k + 3) * n_waves;
                const f4* p0 = (const f4*)(logits + r0 * (size_t)C);
                const f4* p1 = (const f4*)(logits + r1 * (size_t)C);
                const f4* p2 = (const f4*)(logits + r2 * (size_t)C);
                const f4* p3 = (const f4*)(logits + r3 * (size_t)C);

                // 16 independent loads, named regs (no runtime-indexed arrays).
                f4 a0 = k0 ? p0[c0] : fz;
                f4 a1 = k1 ? p0[c1] : fz;
                f4 a2 = k2 ? p0[c2] : fz;
                f4 a3 = k3 ? p0[c3] : fz;
                f4 b0 = k0 ? p1[c0] : fz;
                f4 b1 = k1 ? p1[c1] : fz;
                f4 b2 = k2 ? p1[c2] : fz;
                f4 b3 = k3 ? p1[c3] : fz;
                f4 d0 = k0 ? p2[c0] : fz;
                f4 d1 = k1 ? p2[c1] : fz;
                f4 d2 = k2 ? p2[c2] : fz;
                f4 d3 = k3 ? p2[c3] : fz;
                f4 e0 = k0 ? p3[c0] : fz;
                f4 e1 = k1 ? p3[c1] : fz;
                f4 e2 = k2 ? p3[c2] : fz;
                f4 e3 = k3 ? p3[c3] : fz;

                float s0 = sq4(a3, sq4(a2, sq4(a1, sq4(a0, 0.0f))));
                float s1 = sq4(b3, sq4(b2, sq4(b1, sq4(b0, 0.0f))));
                float s2 = sq4(d3, sq4(d2, sq4(d1, sq4(d0, 0.0f))));
                float s3 = sq4(e3, sq4(e2, sq4(e1, sq4(e0, 0.0f))));

                // scalar tail (no-op when C % 4 == 0)
                for (int cc = tail + lane; cc < C; cc += WAVE) {
                    float v0 = logits[r0 * (size_t)C + cc];
                    float v1 = logits[r1 * (size_t)C + cc];
                    float v2 = logits[r2 * (size_t)C + cc];
                    float v3 = logits[r3 * (size_t)C + cc];
                    s0 = fmaf(v0, v0, s0);
                    s1 = fmaf(v1, v1, s1);
                    s2 = fmaf(v2, v2, s2);
                    s3 = fmaf(v3, v3, s3);
                }

                // butterfly: every lane ends with all four row-sums
                #pragma unroll
                for (int off = 1; off < WAVE; off <<= 1) {
                    s0 += __shfl_xor(s0, off, WAVE);
                    s1 += __shfl_xor(s1, off, WAVE);
                    s2 += __shfl_xor(s2, off, WAVE);
                    s3 += __shfl_xor(s3, off, WAVE);
                }

                // lanes k..k+3 own these rows' dots
                const int t = lane - k;
                if (t >= 0 && t < 4) {
                    const float ss = (t == 0) ? s0 : (t == 1) ? s1 : (t == 2) ? s2 : s3;
                    const float norm = sqrtf(ss);
                    local += (1.0f - my_dot / fmaxf(norm, EPSF)) * inv_n;
                }
            }
        } else {
            // ---- generic path (C > 1024): dynamic-stride streaming, 4 rows in flight
            for (; k + 3 < nrows; k += 4) {
                const size_t r0 = (size_t)g0 + (size_t)(k    ) * n_waves;
                const size_t r1 = (size_t)g0 + (size_t)(k + 1) * n_waves;
                const size_t r2 = (size_t)g0 + (size_t)(k + 2) * n_waves;
                const size_t r3 = (size_t)g0 + (size_t)(k + 3) * n_waves;
                const f4* p0 = (const f4*)(logits + r0 * (size_t)C);
                const f4* p1 = (const f4*)(logits + r1 * (size_t)C);
                const f4* p2 = (const f4*)(logits + r2 * (size_t)C);
                const f4* p3 = (const f4*)(logits + r3 * (size_t)C);

                float s0 = 0.0f, s1 = 0.0f, s2 = 0.0f, s3 = 0.0f;
                for (int cc = lane; cc < nvec; cc += WAVE) {
                    f4 a = p0[cc];
                    f4 b = p1[cc];
                    f4 d = p2[cc];
                    f4 e = p3[cc];
                    s0 = sq4(a, s0);
                    s1 = sq4(b, s1);
                    s2 = sq4(d, s2);
                    s3 = sq4(e, s3);
                }
                for (int cc = tail + lane; cc < C; cc += WAVE) {
                    float v0 = logits[r0 * (size_t)C + cc];
                    float v1 = logits[r1 * (size_t)C + cc];
                    float v2 = logits[r2 * (size_t)C + cc];
                    float v3 = logits[r3 * (size_t)C + cc];
                    s0 = fmaf(v0, v0, s0);
                    s1 = fmaf(v1, v1, s1);
                    s2 = fmaf(v2, v2, s2);
                    s3 = fmaf(v3, v3, s3);
                }
                #pragma unroll
                for (int off = 1; off < WAVE; off <<= 1) {
                    s0 += __shfl_xor(s0, off, WAVE);
                    s1 += __shfl_xor(s1, off, WAVE);
                    s2 += __shfl_xor(s2, off, WAVE);
                    s3 += __shfl_xor(s3, off, WAVE);
                }
                const int t = lane - k;
                if (t >= 0 && t < 4) {
                    const float ss = (t == 0) ? s0 : (t == 1) ? s1 : (t == 2) ? s2 : s3;
                    const float norm = sqrtf(ss);
                    local += (1.0f - my_dot / fmaxf(norm, EPSF)) * inv_n;
                }
            }
        }

        // ---- remainder single rows
        for (; k < nrows; ++k) {
            const size_t r = (size_t)g0 + (size_t)k * n_waves;
            const f4* p = (const f4*)(logits + r * (size_t)C);
            float ss = 0.0f;
            for (int cc = lane; cc < nvec; cc += WAVE) ss = sq4(p[cc], ss);
            for (int cc = tail + lane; cc < C; cc += WAVE) {
                float v = logits[r * (size_t)C + cc];
                ss = fmaf(v, v, ss);
            }
            #pragma unroll
            for (int off = 1; off < WAVE; off <<= 1)
                ss += __shfl_xor(ss, off, WAVE);
            if (lane == k) {
                const float norm = sqrtf(ss);
                local += (1.0f - my_dot / fmaxf(norm, EPSF)) * inv_n;
            }
        }
    }

    // ---- block reduction: wave butterfly-down, one LDS slot per wave, one atomic per block
    #pragma unroll
    for (int off = 32; off > 0; off >>= 1)
        local += __shfl_down(local, off, WAVE);

    __shared__ float sdata[BLOCK / WAVE];
    const int w = threadIdx.x >> 6;
    if (lane == 0) sdata[w] = local;
    __syncthreads();
    if (threadIdx.x == 0) {
        float s = 0.0f;
        #pragma unroll
        for (int i = 0; i < BLOCK / WAVE; ++i) s += sdata[i];
        atomicAdd(out, s);
    }
}

extern "C" void kernel_launch(void* const* d_in, const int* in_sizes, int n_in,
                              void* d_out, int out_size, void* d_ws, size_t ws_size,
                              hipStream_t stream) {
    const float* logits = (const float*)d_in[0];
    const int*   labels = (const int*)d_in[1];
    float*       out    = (float*)d_out;

    const int N = in_sizes[1];
    const int C = in_sizes[0] / N;
    const float inv_n = 1.0f / (float)N;

    // d_out is poisoned to 0xAA before every timed launch — zero it (capturable)
    hipMemsetAsync(d_out, 0, sizeof(float), stream);

    cosine_loss_kernel<<<GRID, BLOCK, 0, stream>>>(logits, labels, out, N, C, inv_n);
}

// Round 3
// 658.168 us; speedup vs baseline: 1.0116x; 1.0116x over previous
//
#include <hip/hip_runtime.h>

#define WAVE 64
#define BLOCK 256
#define GRID 2048
#define EPSF 1e-8f

typedef float f4 __attribute__((ext_vector_type(4)));

__device__ __forceinline__ float sq4(f4 v, float acc) {
    return fmaf(v.x, v.x, fmaf(v.y, v.y, fmaf(v.z, v.z, fmaf(v.w, v.w, acc))));
}

// Phase 1: per-block partial of mean(1 - cos).
// USE_WS=1: plain store to part[blockIdx.x] (no atomics).
// USE_WS=0: fallback — device-scope atomicAdd into *part (out), as in R1.
template <int USE_WS>
__global__ __launch_bounds__(BLOCK) void cosine_loss_partial(
    const float* __restrict__ logits,
    const int* __restrict__ labels,
    float* __restrict__ part,
    int N, int C, float inv_n)
{
    const int lane    = threadIdx.x & (WAVE - 1);
    const int wave_id = (blockIdx.x * BLOCK + threadIdx.x) >> 6;
    const int n_waves = (gridDim.x * BLOCK) >> 6;

    const int nvec = C >> 2;          // full float4 chunks per row
    const int tail = nvec << 2;       // first scalar-tail column

    float local = 0.0f;

    // Super-groups of up to 64 rows per wave; lane k owns row g0 + k*n_waves.
    // Label+dot gathers happen ONCE per super-group.
    for (int g0 = wave_id; g0 < N; g0 += (n_waves << 6)) {
        const long long my_r = (long long)g0 + (long long)lane * (long long)n_waves;
        float my_dot = 0.0f;
        if (my_r < (long long)N) {
            const int lbl = labels[my_r];
            my_dot = logits[(size_t)my_r * (size_t)C + (size_t)lbl];
        }

        int nrows = (N - g0 + n_waves - 1) / n_waves;   // valid rows this super-group
        if (nrows > 64) nrows = 64;

        int k = 0;

        if (nvec <= 256) {
            // ---- fast path (C <= 1024): whole row = <=4 chunks/lane.
            const int c0 = lane;
            const int c1 = lane + 64;
            const int c2 = lane + 128;
            const int c3 = lane + 192;
            const bool k0 = c0 < nvec;
            const bool k1 = c1 < nvec;
            const bool k2 = c2 < nvec;
            const bool k3 = c3 < nvec;
            const f4 fz = {0.0f, 0.0f, 0.0f, 0.0f};

            for (; k + 3 < nrows; k += 4) {
                const size_t r0 = (size_t)g0 + (size_t)(k    ) * n_waves;
                const size_t r1 = (size_t)g0 + (size_t)(k + 1) * n_waves;
                const size_t r2 = (size_t)g0 + (size_t)(k + 2) * n_waves;
                const size_t r3 = (size_t)g0 + (size_t)(k + 3) * n_waves;
                const f4* p0 = (const f4*)(logits + r0 * (size_t)C);
                const f4* p1 = (const f4*)(logits + r1 * (size_t)C);
                const f4* p2 = (const f4*)(logits + r2 * (size_t)C);
                const f4* p3 = (const f4*)(logits + r3 * (size_t)C);

                f4 a0 = k0 ? p0[c0] : fz;
                f4 a1 = k1 ? p0[c1] : fz;
                f4 a2 = k2 ? p0[c2] : fz;
                f4 a3 = k3 ? p0[c3] : fz;
                f4 b0 = k0 ? p1[c0] : fz;
                f4 b1 = k1 ? p1[c1] : fz;
                f4 b2 = k2 ? p1[c2] : fz;
                f4 b3 = k3 ? p1[c3] : fz;
                f4 d0 = k0 ? p2[c0] : fz;
                f4 d1 = k1 ? p2[c1] : fz;
                f4 d2 = k2 ? p2[c2] : fz;
                f4 d3 = k3 ? p2[c3] : fz;
                f4 e0 = k0 ? p3[c0] : fz;
                f4 e1 = k1 ? p3[c1] : fz;
                f4 e2 = k2 ? p3[c2] : fz;
                f4 e3 = k3 ? p3[c3] : fz;

                float s0 = sq4(a3, sq4(a2, sq4(a1, sq4(a0, 0.0f))));
                float s1 = sq4(b3, sq4(b2, sq4(b1, sq4(b0, 0.0f))));
                float s2 = sq4(d3, sq4(d2, sq4(d1, sq4(d0, 0.0f))));
                float s3 = sq4(e3, sq4(e2, sq4(e1, sq4(e0, 0.0f))));

                for (int cc = tail + lane; cc < C; cc += WAVE) {
                    float v0 = logits[r0 * (size_t)C + cc];
                    float v1 = logits[r1 * (size_t)C + cc];
                    float v2 = logits[r2 * (size_t)C + cc];
                    float v3 = logits[r3 * (size_t)C + cc];
                    s0 = fmaf(v0, v0, s0);
                    s1 = fmaf(v1, v1, s1);
                    s2 = fmaf(v2, v2, s2);
                    s3 = fmaf(v3, v3, s3);
                }

                #pragma unroll
                for (int off = 1; off < WAVE; off <<= 1) {
                    s0 += __shfl_xor(s0, off, WAVE);
                    s1 += __shfl_xor(s1, off, WAVE);
                    s2 += __shfl_xor(s2, off, WAVE);
                    s3 += __shfl_xor(s3, off, WAVE);
                }

                const int t = lane - k;
                if (t >= 0 && t < 4) {
                    const float ss = (t == 0) ? s0 : (t == 1) ? s1 : (t == 2) ? s2 : s3;
                    const float norm = sqrtf(ss);
                    local += (1.0f - my_dot / fmaxf(norm, EPSF)) * inv_n;
                }
            }
        } else {
            // ---- generic path (C > 1024)
            for (; k + 3 < nrows; k += 4) {
                const size_t r0 = (size_t)g0 + (size_t)(k    ) * n_waves;
                const size_t r1 = (size_t)g0 + (size_t)(k + 1) * n_waves;
                const size_t r2 = (size_t)g0 + (size_t)(k + 2) * n_waves;
                const size_t r3 = (size_t)g0 + (size_t)(k + 3) * n_waves;
                const f4* p0 = (const f4*)(logits + r0 * (size_t)C);
                const f4* p1 = (const f4*)(logits + r1 * (size_t)C);
                const f4* p2 = (const f4*)(logits + r2 * (size_t)C);
                const f4* p3 = (const f4*)(logits + r3 * (size_t)C);

                float s0 = 0.0f, s1 = 0.0f, s2 = 0.0f, s3 = 0.0f;
                for (int cc = lane; cc < nvec; cc += WAVE) {
                    f4 a = p0[cc];
                    f4 b = p1[cc];
                    f4 d = p2[cc];
                    f4 e = p3[cc];
                    s0 = sq4(a, s0);
                    s1 = sq4(b, s1);
                    s2 = sq4(d, s2);
                    s3 = sq4(e, s3);
                }
                for (int cc = tail + lane; cc < C; cc += WAVE) {
                    float v0 = logits[r0 * (size_t)C + cc];
                    float v1 = logits[r1 * (size_t)C + cc];
                    float v2 = logits[r2 * (size_t)C + cc];
                    float v3 = logits[r3 * (size_t)C + cc];
                    s0 = fmaf(v0, v0, s0);
                    s1 = fmaf(v1, v1, s1);
                    s2 = fmaf(v2, v2, s2);
                    s3 = fmaf(v3, v3, s3);
                }
                #pragma unroll
                for (int off = 1; off < WAVE; off <<= 1) {
                    s0 += __shfl_xor(s0, off, WAVE);
                    s1 += __shfl_xor(s1, off, WAVE);
                    s2 += __shfl_xor(s2, off, WAVE);
                    s3 += __shfl_xor(s3, off, WAVE);
                }
                const int t = lane - k;
                if (t >= 0 && t < 4) {
                    const float ss = (t == 0) ? s0 : (t == 1) ? s1 : (t == 2) ? s2 : s3;
                    const float norm = sqrtf(ss);
                    local += (1.0f - my_dot / fmaxf(norm, EPSF)) * inv_n;
                }
            }
        }

        // ---- remainder single rows
        for (; k < nrows; ++k) {
            const size_t r = (size_t)g0 + (size_t)k * n_waves;
            const f4* p = (const f4*)(logits + r * (size_t)C);
            float ss = 0.0f;
            for (int cc = lane; cc < nvec; cc += WAVE) ss = sq4(p[cc], ss);
            for (int cc = tail + lane; cc < C; cc += WAVE) {
                float v = logits[r * (size_t)C + cc];
                ss = fmaf(v, v, ss);
            }
            #pragma unroll
            for (int off = 1; off < WAVE; off <<= 1)
                ss += __shfl_xor(ss, off, WAVE);
            if (lane == k) {
                const float norm = sqrtf(ss);
                local += (1.0f - my_dot / fmaxf(norm, EPSF)) * inv_n;
            }
        }
    }

    // ---- block reduction: wave shuffle-down, one LDS slot per wave.
    #pragma unroll
    for (int off = 32; off > 0; off >>= 1)
        local += __shfl_down(local, off, WAVE);

    __shared__ float sdata[BLOCK / WAVE];
    const int w = threadIdx.x >> 6;
    if (lane == 0) sdata[w] = local;
    __syncthreads();
    if (threadIdx.x == 0) {
        float s = 0.0f;
        #pragma unroll
        for (int i = 0; i < BLOCK / WAVE; ++i) s += sdata[i];
        if (USE_WS) part[blockIdx.x] = s;      // plain store, no contention
        else        atomicAdd(part, s);        // fallback: contended atomic
    }
}

// Phase 2: sum GRID partials, write the scalar result (overwrites poisoned out).
__global__ __launch_bounds__(BLOCK) void reduce_partials(
    const float* __restrict__ part,
    float* __restrict__ out,
    int nparts)
{
    const int lane = threadIdx.x & (WAVE - 1);
    float s = 0.0f;
    for (int i = threadIdx.x; i < nparts; i += BLOCK)
        s += part[i];
    #pragma unroll
    for (int off = 32; off > 0; off >>= 1)
        s += __shfl_down(s, off, WAVE);

    __shared__ float sdata[BLOCK / WAVE];
    const int w = threadIdx.x >> 6;
    if (lane == 0) sdata[w] = s;
    __syncthreads();
    if (threadIdx.x == 0) {
        float t = 0.0f;
        #pragma unroll
        for (int i = 0; i < BLOCK / WAVE; ++i) t += sdata[i];
        *out = t;
    }
}

extern "C" void kernel_launch(void* const* d_in, const int* in_sizes, int n_in,
                              void* d_out, int out_size, void* d_ws, size_t ws_size,
                              hipStream_t stream) {
    const float* logits = (const float*)d_in[0];
    const int*   labels = (const int*)d_in[1];
    float*       out    = (float*)d_out;

    const int N = in_sizes[1];
    const int C = in_sizes[0] / N;
    const float inv_n = 1.0f / (float)N;

    // Defensive: only use the workspace if it actually exists and is big
    // enough — R2's unconditional ws writes are the prime suspect for the
    // double container failure.
    const bool have_ws = (d_ws != nullptr) && (ws_size >= (size_t)GRID * sizeof(float));

    if (have_ws) {
        float* part = (float*)d_ws;
        cosine_loss_partial<1><<<GRID, BLOCK, 0, stream>>>(logits, labels, part, N, C, inv_n);
        reduce_partials<<<1, BLOCK, 0, stream>>>(part, out, GRID);
    } else {
        // R1-style fallback: memset out, atomicAdd finish.
        hipMemsetAsync(d_out, 0, sizeof(float), stream);
        cosine_loss_partial<0><<<GRID, BLOCK, 0, stream>>>(logits, labels, out, N, C, inv_n);
    }
}